// Round 1
// baseline (983.548 us; speedup 1.0000x reference)
//
#include <hip/hip_runtime.h>
#include <hip/hip_bf16.h>

#define B_ 16

// ---------------- conv1: (16,3,512,512) -> conv s2 p1 -> relu -> pool2 -> (16,64,128,128)
__global__ __launch_bounds__(256) void k_conv1(const float* __restrict__ x,
                                               const float* __restrict__ w1,
                                               const float* __restrict__ b1,
                                               float* __restrict__ y1) {
    const int b = blockIdx.y;
    const int tile = blockIdx.x;                 // 64 tiles: 8x8 of 16x16 pooled pixels
    const int ty = (tile >> 3) * 16 + (threadIdx.x >> 4);
    const int tx = (tile & 7) * 16 + (threadIdx.x & 15);
    const float* xb = x + (size_t)b * 3 * 512 * 512;

    float m[64];
#pragma unroll
    for (int i = 0; i < 64; ++i) m[i] = -1e30f;

    for (int dy = 0; dy < 2; ++dy)
    for (int dx = 0; dx < 2; ++dx) {
        const int oy = ty * 2 + dy, ox = tx * 2 + dx;   // conv coords in 256x256
        float in[27];
#pragma unroll
        for (int c = 0; c < 3; ++c)
#pragma unroll
        for (int ky = 0; ky < 3; ++ky)
#pragma unroll
        for (int kx = 0; kx < 3; ++kx) {
            const int iy = oy * 2 - 1 + ky, ix = ox * 2 - 1 + kx;
            float v = 0.f;
            if (iy >= 0 && iy < 512 && ix >= 0 && ix < 512)
                v = xb[((size_t)c * 512 + iy) * 512 + ix];
            in[(c * 3 + ky) * 3 + kx] = v;
        }
#pragma unroll 4
        for (int co = 0; co < 64; ++co) {
            float s = 0.f;
#pragma unroll
            for (int j = 0; j < 27; ++j) s += in[j] * w1[co * 27 + j];
            m[co] = fmaxf(m[co], s);
        }
    }
#pragma unroll 4
    for (int co = 0; co < 64; ++co) {
        float r = fmaxf(m[co] + b1[co], 0.f);
        y1[(((size_t)b * 64 + co) * 128 + ty) * 128 + tx] = r;
    }
}

// ---------------- conv2: (16,64,128,128) -> conv s2 p1 -> relu -> pool2 -> (16,128,32,32)
__global__ __launch_bounds__(256) void k_conv2(const float* __restrict__ y1,
                                               const float* __restrict__ w2,
                                               const float* __restrict__ b2,
                                               float* __restrict__ y2) {
    const int b = blockIdx.z;
    const int cog = blockIdx.y;                  // 8 groups of 16 co
    const int tile = blockIdx.x;                 // 4 tiles: 2x2 of 16x16 in 32x32 pooled
    const int ty = (tile >> 1) * 16 + (threadIdx.x >> 4);
    const int tx = (tile & 1) * 16 + (threadIdx.x & 15);
    const float* xb = y1 + (size_t)b * 64 * 128 * 128;

    float pooled[16];
#pragma unroll
    for (int i = 0; i < 16; ++i) pooled[i] = -1e30f;

    for (int dy = 0; dy < 2; ++dy)
    for (int dx = 0; dx < 2; ++dx) {
        const int oy = ty * 2 + dy, ox = tx * 2 + dx;   // conv coords in 64x64
        float acc[16];
#pragma unroll
        for (int i = 0; i < 16; ++i) acc[i] = 0.f;
        for (int ci = 0; ci < 64; ++ci) {
            float in[9];
#pragma unroll
            for (int ky = 0; ky < 3; ++ky)
#pragma unroll
            for (int kx = 0; kx < 3; ++kx) {
                const int iy = oy * 2 - 1 + ky, ix = ox * 2 - 1 + kx;
                float v = 0.f;
                if (iy >= 0 && iy < 128 && ix >= 0 && ix < 128)
                    v = xb[((size_t)ci * 128 + iy) * 128 + ix];
                in[ky * 3 + kx] = v;
            }
            const float* wp = w2 + ((size_t)(cog * 16) * 64 + ci) * 9;
#pragma unroll
            for (int co = 0; co < 16; ++co) {
#pragma unroll
                for (int j = 0; j < 9; ++j) acc[co] += in[j] * wp[(size_t)co * 576 + j];
            }
        }
#pragma unroll
        for (int co = 0; co < 16; ++co) pooled[co] = fmaxf(pooled[co], acc[co]);
    }
#pragma unroll
    for (int co = 0; co < 16; ++co) {
        const int c = cog * 16 + co;
        float r = fmaxf(pooled[co] + b2[c], 0.f);
        y2[(((size_t)b * 128 + c) * 32 + ty) * 32 + tx] = r;
    }
}

// ---------------- conv3: (16,128,32,32) -> conv s2 p1 -> relu -> pool2 -> (16,256,8,8)
__global__ __launch_bounds__(256) void k_conv3(const float* __restrict__ y2,
                                               const float* __restrict__ w3,
                                               const float* __restrict__ b3,
                                               float* __restrict__ y3) {
    const int b = blockIdx.y;
    const int cb = blockIdx.x;                   // 16 blocks of 16 co
    const int px = threadIdx.x & 63;             // 8x8 pooled pixels
    const int chunk = threadIdx.x >> 6;          // 4 chunks of 4 co
    const int py = px >> 3, pxx = px & 7;
    const int co0 = cb * 16 + chunk * 4;
    const float* xb = y2 + (size_t)b * 128 * 32 * 32;

    float pooled[4];
#pragma unroll
    for (int i = 0; i < 4; ++i) pooled[i] = -1e30f;

    for (int dy = 0; dy < 2; ++dy)
    for (int dx = 0; dx < 2; ++dx) {
        const int oy = py * 2 + dy, ox = pxx * 2 + dx;  // conv coords in 16x16
        float acc[4] = {0.f, 0.f, 0.f, 0.f};
        for (int ci = 0; ci < 128; ++ci) {
            float in[9];
#pragma unroll
            for (int ky = 0; ky < 3; ++ky)
#pragma unroll
            for (int kx = 0; kx < 3; ++kx) {
                const int iy = oy * 2 - 1 + ky, ix = ox * 2 - 1 + kx;
                float v = 0.f;
                if (iy >= 0 && iy < 32 && ix >= 0 && ix < 32)
                    v = xb[((size_t)ci * 32 + iy) * 32 + ix];
                in[ky * 3 + kx] = v;
            }
            const float* wp = w3 + ((size_t)co0 * 128 + ci) * 9;
#pragma unroll
            for (int co = 0; co < 4; ++co) {
#pragma unroll
                for (int j = 0; j < 9; ++j) acc[co] += in[j] * wp[(size_t)co * 1152 + j];
            }
        }
#pragma unroll
        for (int co = 0; co < 4; ++co) pooled[co] = fmaxf(pooled[co], acc[co]);
    }
#pragma unroll
    for (int co = 0; co < 4; ++co) {
        const int c = co0 + co;
        float r = fmaxf(pooled[co] + b3[c], 0.f);
        y3[(((size_t)b * 256 + c) * 8 + py) * 8 + pxx] = r;
    }
}

// ---------------- conv4 + relu + spatial mean: (16,256,8,8) -> feats (16,512)
__global__ __launch_bounds__(256) void k_conv4(const float* __restrict__ y3,
                                               const float* __restrict__ w4,
                                               const float* __restrict__ b4,
                                               float* __restrict__ feats) {
    const int b = blockIdx.y;
    const int cob = blockIdx.x;                  // 8 blocks of 64 co
    const int lane = threadIdx.x & 63;
    const int oy = threadIdx.x >> 6;             // 0..3 output rows
    const int co = cob * 64 + lane;

    __shared__ float sA[16384];                  // full y3[b] slice (64 KB)
    const float* xb = y3 + (size_t)b * 256 * 64;
    for (int i = threadIdx.x; i < 16384; i += 256) sA[i] = xb[i];
    __syncthreads();

    float acc[4] = {0.f, 0.f, 0.f, 0.f};         // ox = 0..3
    const float* wp = w4 + (size_t)co * 2304;
    for (int ci = 0; ci < 256; ++ci) {
        float row[3][8];
#pragma unroll
        for (int ky = 0; ky < 3; ++ky) {
            const int iy = 2 * oy - 1 + ky;
            const bool okY = (iy >= 0 && iy < 8);
#pragma unroll
            for (int c8 = 0; c8 < 8; ++c8)
                row[ky][c8] = okY ? sA[(ci * 8 + iy) * 8 + c8] : 0.f;
        }
        float w[9];
#pragma unroll
        for (int j = 0; j < 9; ++j) w[j] = wp[ci * 9 + j];
#pragma unroll
        for (int ox = 0; ox < 4; ++ox) {
#pragma unroll
            for (int ky = 0; ky < 3; ++ky)
#pragma unroll
            for (int kx = 0; kx < 3; ++kx) {
                const int ix = 2 * ox - 1 + kx;
                if (ix >= 0 && ix < 8) acc[ox] += row[ky][ix] * w[ky * 3 + kx];
            }
        }
    }
    const float bias = b4[co];
    float s = 0.f;
#pragma unroll
    for (int ox = 0; ox < 4; ++ox) s += fmaxf(acc[ox] + bias, 0.f);

    __syncthreads();                              // done reading sA; reuse for reduction
    sA[oy * 64 + lane] = s;
    __syncthreads();
    if (threadIdx.x < 64) {
        float t = sA[lane] + sA[64 + lane] + sA[128 + lane] + sA[192 + lane];
        feats[b * 512 + co] = t * (1.f / 16.f);
    }
}

// ---------------- head: feats -> logits -> softmax -> VLAD residual v (16, 32768)
__global__ __launch_bounds__(256) void k_head(const float* __restrict__ feats,
                                              const float* __restrict__ wv,
                                              const float* __restrict__ bv,
                                              const float* __restrict__ centroids,
                                              float* __restrict__ v) {
    const int b = blockIdx.x;
    __shared__ float sf[512];
    __shared__ float sl[64];
    __shared__ float sa[64];
    for (int i = threadIdx.x; i < 512; i += 256) sf[i] = feats[b * 512 + i];
    __syncthreads();
    if (threadIdx.x < 64) {
        const int k = threadIdx.x;
        float s = bv[k];
        for (int c = 0; c < 512; ++c) s += sf[c] * wv[(size_t)k * 512 + c];
        sl[k] = s;
    }
    __syncthreads();
    if (threadIdx.x < 64) {
        const int k = threadIdx.x;
        float m = -1e30f;
        for (int i = 0; i < 64; ++i) m = fmaxf(m, sl[i]);
        float sum = 0.f;
        for (int i = 0; i < 64; ++i) sum += __expf(sl[i] - m);
        sa[k] = __expf(sl[k] - m) / sum;
    }
    __syncthreads();
    for (int i4 = threadIdx.x * 4; i4 < 32768; i4 += 1024) {
        const int k = i4 >> 9;
        const float a_ = sa[k];
        const float4 c4 = *(const float4*)(centroids + i4);
        const float4 f4 = *(const float4*)(&sf[i4 & 511]);
        float4 o;
        o.x = a_ * (f4.x - c4.x);
        o.y = a_ * (f4.y - c4.y);
        o.z = a_ * (f4.z - c4.z);
        o.w = a_ * (f4.w - c4.w);
        *(float4*)(v + (size_t)b * 32768 + i4) = o;
    }
}

// ---------------- fc1: d1[b,d] = relu(sum_j v[b,j] * fw1[d,j] + fb1[d]), (16,256)
__global__ __launch_bounds__(256) void k_fc1(const float* __restrict__ v,
                                             const float* __restrict__ fw1,
                                             const float* __restrict__ fb1,
                                             float* __restrict__ d1) {
    const int d = blockIdx.x;                    // 256 blocks
    float acc[16];
#pragma unroll
    for (int i = 0; i < 16; ++i) acc[i] = 0.f;
    const float* wrow = fw1 + (size_t)d * 32768;
    for (int j4 = threadIdx.x * 4; j4 < 32768; j4 += 1024) {
        const float4 w = *(const float4*)(wrow + j4);
#pragma unroll
        for (int b = 0; b < 16; ++b) {
            const float4 vv = *(const float4*)(v + (size_t)b * 32768 + j4);
            acc[b] += w.x * vv.x + w.y * vv.y + w.z * vv.z + w.w * vv.w;
        }
    }
#pragma unroll
    for (int b = 0; b < 16; ++b) {
        float s = acc[b];
        for (int off = 32; off >= 1; off >>= 1) s += __shfl_down(s, off, 64);
        acc[b] = s;
    }
    __shared__ float red[4][16];
    const int wid = threadIdx.x >> 6, lane = threadIdx.x & 63;
    if (lane == 0) {
#pragma unroll
        for (int b = 0; b < 16; ++b) red[wid][b] = acc[b];
    }
    __syncthreads();
    if (threadIdx.x < 16) {
        const int b = threadIdx.x;
        float s = red[0][b] + red[1][b] + red[2][b] + red[3][b] + fb1[d];
        d1[b * 256 + d] = fmaxf(s, 0.f);
    }
}

// ---------------- fc2 + L2 norm: out[b,d] = (d1[b]@fw2[d]+fb2[d]) / ||row||
__global__ __launch_bounds__(256) void k_fc2(const float* __restrict__ d1,
                                             const float* __restrict__ fw2,
                                             const float* __restrict__ fb2,
                                             float* __restrict__ out) {
    const int b = blockIdx.x;
    const int dd = threadIdx.x;
    __shared__ float sd[256];
    __shared__ float sq[256];
    sd[dd] = d1[b * 256 + dd];
    __syncthreads();
    float s = fb2[dd];
    for (int j = 0; j < 256; ++j) s += sd[j] * fw2[(size_t)dd * 256 + j];
    sq[dd] = s * s;
    __syncthreads();
    for (int off = 128; off >= 1; off >>= 1) {
        if (dd < off) sq[dd] += sq[dd + off];
        __syncthreads();
    }
    const float inv = rsqrtf(sq[0]);
    out[b * 256 + dd] = s * inv;
}

extern "C" void kernel_launch(void* const* d_in, const int* in_sizes, int n_in,
                              void* d_out, int out_size, void* d_ws, size_t ws_size,
                              hipStream_t stream) {
    const float* x    = (const float*)d_in[0];
    const float* w1   = (const float*)d_in[1];
    const float* b1   = (const float*)d_in[2];
    const float* w2   = (const float*)d_in[3];
    const float* b2   = (const float*)d_in[4];
    const float* w3   = (const float*)d_in[5];
    const float* b3   = (const float*)d_in[6];
    const float* w4   = (const float*)d_in[7];
    const float* b4   = (const float*)d_in[8];
    const float* wv   = (const float*)d_in[9];
    const float* bv   = (const float*)d_in[10];
    const float* cen  = (const float*)d_in[11];
    const float* fw1  = (const float*)d_in[12];
    const float* fb1  = (const float*)d_in[13];
    const float* fw2  = (const float*)d_in[14];
    const float* fb2  = (const float*)d_in[15];
    float* out = (float*)d_out;

    float* ws    = (float*)d_ws;
    float* y1    = ws;                       // 16*64*128*128 = 16777216
    float* y2    = y1 + 16777216;            // 16*128*32*32  = 2097152
    float* y3    = y2 + 2097152;             // 16*256*8*8    = 262144
    float* feats = y3 + 262144;              // 16*512        = 8192
    float* vbuf  = feats + 8192;             // 16*32768      = 524288
    float* d1    = vbuf + 524288;            // 16*256        = 4096

    k_conv1<<<dim3(64, 16), 256, 0, stream>>>(x, w1, b1, y1);
    k_conv2<<<dim3(4, 8, 16), 256, 0, stream>>>(y1, w2, b2, y2);
    k_conv3<<<dim3(16, 16), 256, 0, stream>>>(y2, w3, b3, y3);
    k_conv4<<<dim3(8, 16), 256, 0, stream>>>(y3, w4, b4, feats);
    k_head<<<16, 256, 0, stream>>>(feats, wv, bv, cen, vbuf);
    k_fc1<<<256, 256, 0, stream>>>(vbuf, fw1, fb1, d1);
    k_fc2<<<16, 256, 0, stream>>>(d1, fw2, fb2, out);
}

// Round 2
// 329.312 us; speedup vs baseline: 2.9867x; 2.9867x over previous
//
#include <hip/hip_runtime.h>
#include <hip/hip_bf16.h>

typedef unsigned short ushort_t;
typedef short bf16x8 __attribute__((ext_vector_type(8)));
typedef float f32x4 __attribute__((ext_vector_type(4)));

__device__ __forceinline__ ushort_t f2b(float f) {
    __hip_bfloat16 h = __float2bfloat16(f);
    return *reinterpret_cast<ushort_t*>(&h);
}
__device__ __forceinline__ float b2f(short v) {
    union { unsigned int u; float f; } cv;
    cv.u = ((unsigned int)(ushort_t)v) << 16;
    return cv.f;
}

// ---------------- weight repack: w2 (128,64,3,3) -> B-fragment order, bf16
// layout: [kc(18)][g16(8)][lane(64)][8], k = kc*32 + (lane>>4)*8 + j, K order = tap*64+ci
__global__ __launch_bounds__(256) void k_pack2(const float* __restrict__ w2, ushort_t* __restrict__ o) {
    const int slot = blockIdx.x * 256 + threadIdx.x;      // 9216 slots
    const int lane = slot & 63, g = (slot >> 6) & 7, kc = slot >> 9;
    const int k0 = kc * 32 + ((lane >> 4) << 3);
    const int tap = k0 >> 6, cib = k0 & 63;
    const int ky = tap >= 6 ? 2 : (tap >= 3 ? 1 : 0), kx = tap - ky * 3;
    const int co = g * 16 + (lane & 15);
#pragma unroll
    for (int j = 0; j < 8; ++j)
        o[slot * 8 + j] = f2b(w2[((co * 64 + cib + j) * 3 + ky) * 3 + kx]);
}

// w3 (256,128,3,3): [kc(36)][g16(16)][lane][8], K order = tap*128+ci
__global__ __launch_bounds__(256) void k_pack3(const float* __restrict__ w3, ushort_t* __restrict__ o) {
    const int slot = blockIdx.x * 256 + threadIdx.x;      // 36864 slots
    const int lane = slot & 63, g = (slot >> 6) & 15, kc = slot >> 10;
    const int k0 = kc * 32 + ((lane >> 4) << 3);
    const int tap = k0 >> 7, cib = k0 & 127;
    const int ky = tap >= 6 ? 2 : (tap >= 3 ? 1 : 0), kx = tap - ky * 3;
    const int co = g * 16 + (lane & 15);
#pragma unroll
    for (int j = 0; j < 8; ++j)
        o[slot * 8 + j] = f2b(w3[((co * 128 + cib + j) * 3 + ky) * 3 + kx]);
}

// w4 (512,256,3,3) -> [co][t][ci] fp32
__global__ __launch_bounds__(256) void k_pack4(const float* __restrict__ w4, float* __restrict__ o) {
    const int i = blockIdx.x * 256 + threadIdx.x;         // 1179648
    const int ci = i & 255, q = i >> 8;
    const int co = q / 9, t = q - co * 9;
    o[i] = w4[(co * 256 + ci) * 9 + t];
}

// ---------------- conv1: (16,3,512,512) -> s2 p1 relu pool2 -> y1 bf16 NHWC (16,128,128,64)
__global__ __launch_bounds__(256) void k_conv1(const float* __restrict__ x,
                                               const float* __restrict__ w1,
                                               const float* __restrict__ b1,
                                               ushort_t* __restrict__ y1) {
    const int b = blockIdx.y;
    const int tile = blockIdx.x;
    const int ty = (tile >> 3) * 16 + (threadIdx.x >> 4);
    const int tx = (tile & 7) * 16 + (threadIdx.x & 15);
    const float* xb = x + (size_t)b * 3 * 512 * 512;

    float m[64];
#pragma unroll
    for (int i = 0; i < 64; ++i) m[i] = -1e30f;

    for (int dy = 0; dy < 2; ++dy)
    for (int dx = 0; dx < 2; ++dx) {
        const int oy = ty * 2 + dy, ox = tx * 2 + dx;
        float in[27];
#pragma unroll
        for (int c = 0; c < 3; ++c)
#pragma unroll
        for (int ky = 0; ky < 3; ++ky)
#pragma unroll
        for (int kx = 0; kx < 3; ++kx) {
            const int iy = oy * 2 - 1 + ky, ix = ox * 2 - 1 + kx;
            float v = 0.f;
            if (iy >= 0 && iy < 512 && ix >= 0 && ix < 512)
                v = xb[((size_t)c * 512 + iy) * 512 + ix];
            in[(c * 3 + ky) * 3 + kx] = v;
        }
#pragma unroll 4
        for (int co = 0; co < 64; ++co) {
            float s = 0.f;
#pragma unroll
            for (int j = 0; j < 27; ++j) s += in[j] * w1[co * 27 + j];
            m[co] = fmaxf(m[co], s);
        }
    }
    const size_t obase = ((size_t)(b * 128 + ty) * 128 + tx) * 64;
#pragma unroll
    for (int g = 0; g < 8; ++g) {
        float4 pk;
        ushort_t* pu = (ushort_t*)&pk;
#pragma unroll
        for (int j = 0; j < 8; ++j)
            pu[j] = f2b(fmaxf(m[g * 8 + j] + b1[g * 8 + j], 0.f));
        *(float4*)(y1 + obase + g * 8) = pk;
    }
}

// ---------------- conv2 MFMA: y1 bf16 NHWC -> y2 bf16 NHWC (16,32,32,128)
// block: b x conv-row-pair (M=128 = 2 oy x 64 ox) x all 128 co; 4 waves N-split 32
__global__ __launch_bounds__(256) void k_conv2m(const ushort_t* __restrict__ y1,
                                                const ushort_t* __restrict__ wpk2,
                                                const float* __restrict__ b2,
                                                ushort_t* __restrict__ y2) {
    const int b = blockIdx.y;
    const int rp = blockIdx.x;               // pooled row 0..31
    const int oy0 = rp * 2;
    const int tid = threadIdx.x;
    const int wid = tid >> 6, lane = tid & 63;
    const int l15 = lane & 15, kl8 = (lane >> 4) << 3;

    const ushort_t* xb = y1 + (size_t)b * 128 * 128 * 64;
    const f32x4 z4 = {0.f, 0.f, 0.f, 0.f};
    f32x4 acc[8][2];
#pragma unroll
    for (int i = 0; i < 8; ++i) { acc[i][0] = z4; acc[i][1] = z4; }

    const int cb0 = 2 * l15 - 1;             // col base before +32*m4 +kx

#pragma unroll 1
    for (int tap = 0; tap < 9; ++tap) {
        const int ky = tap >= 6 ? 2 : (tap >= 3 ? 1 : 0), kx = tap - ky * 3;
        const int iyA = 2 * oy0 - 1 + ky;    // oy0 row
#pragma unroll
        for (int h = 0; h < 2; ++h) {
            const int ci0 = h * 32;
            const int kc = tap * 2 + h;
            bf16x8 aF[8];
#pragma unroll
            for (int mf = 0; mf < 8; ++mf) {
                const int iy = iyA + 2 * (mf >> 2);
                const int c = cb0 + (mf & 3) * 32 + kx;
                const bool ok = (iy >= 0) && (c >= 0);
                bf16x8 r = {0, 0, 0, 0, 0, 0, 0, 0};
                if (ok) r = *reinterpret_cast<const bf16x8*>(xb + ((size_t)iy * 128 + c) * 64 + ci0 + kl8);
                aF[mf] = r;
            }
            bf16x8 bF[2];
#pragma unroll
            for (int nf = 0; nf < 2; ++nf)
                bF[nf] = *reinterpret_cast<const bf16x8*>(wpk2 + ((size_t)(kc * 8 + wid * 2 + nf) * 64 + lane) * 8);
#pragma unroll
            for (int mf = 0; mf < 8; ++mf)
#pragma unroll
                for (int nf = 0; nf < 2; ++nf)
                    acc[mf][nf] = __builtin_amdgcn_mfma_f32_16x16x32_bf16(aF[mf], bF[nf], acc[mf][nf], 0, 0, 0);
        }
    }
    // epilogue: pool 2x2 (reg pairs = ox pairs, mf vs mf+4 = oy pair) + bias + relu
    const int kg = lane >> 4;
#pragma unroll
    for (int nf = 0; nf < 2; ++nf) {
        const int co = wid * 32 + nf * 16 + l15;
        const float bias = b2[co];
#pragma unroll
        for (int m4 = 0; m4 < 4; ++m4)
#pragma unroll
            for (int p = 0; p < 2; ++p) {
                float v = fmaxf(fmaxf(acc[m4][nf][2 * p], acc[m4][nf][2 * p + 1]),
                                fmaxf(acc[m4 + 4][nf][2 * p], acc[m4 + 4][nf][2 * p + 1]));
                const int px = m4 * 8 + kg * 2 + p;
                y2[((size_t)(b * 32 + rp) * 32 + px) * 128 + co] = f2b(fmaxf(v + bias, 0.f));
            }
    }
}

// ---------------- conv3 MFMA: y2 bf16 NHWC -> y3 bf16 NHWC (16,8,8,256)
// block: (gy: 4 conv rows, gn: 64 co, b); 4 waves N-split 16
__global__ __launch_bounds__(256) void k_conv3m(const ushort_t* __restrict__ y2,
                                                const ushort_t* __restrict__ wpk3,
                                                const float* __restrict__ b3,
                                                ushort_t* __restrict__ y3) {
    const int gy = blockIdx.x, gn = blockIdx.y, b = blockIdx.z;
    const int oy0 = gy * 4;
    const int tid = threadIdx.x;
    const int wid = tid >> 6, lane = tid & 63;
    const int l15 = lane & 15, kl8 = (lane >> 4) << 3;
    const int g16 = gn * 4 + wid;            // global 16-col group
    const int co = g16 * 16 + l15;

    const ushort_t* xb = y2 + (size_t)b * 32 * 32 * 128;
    const f32x4 z4 = {0.f, 0.f, 0.f, 0.f};
    f32x4 acc[4] = {z4, z4, z4, z4};

#pragma unroll 1
    for (int tap = 0; tap < 9; ++tap) {
        const int ky = tap >= 6 ? 2 : (tap >= 3 ? 1 : 0), kx = tap - ky * 3;
        const int iyA = 2 * oy0 - 1 + ky;
        const int c = 2 * l15 - 1 + kx;
        const bool cok = (c >= 0);
#pragma unroll
        for (int h = 0; h < 4; ++h) {
            const int ci0 = h * 32;
            const int kc = tap * 4 + h;
            bf16x8 aF[4];
#pragma unroll
            for (int mf = 0; mf < 4; ++mf) {
                const int iy = iyA + 2 * mf;
                bf16x8 r = {0, 0, 0, 0, 0, 0, 0, 0};
                if (cok && iy >= 0) r = *reinterpret_cast<const bf16x8*>(xb + ((size_t)iy * 32 + c) * 128 + ci0 + kl8);
                aF[mf] = r;
            }
            const bf16x8 bF = *reinterpret_cast<const bf16x8*>(wpk3 + ((size_t)(kc * 16 + g16) * 64 + lane) * 8);
#pragma unroll
            for (int mf = 0; mf < 4; ++mf)
                acc[mf] = __builtin_amdgcn_mfma_f32_16x16x32_bf16(aF[mf], bF, acc[mf], 0, 0, 0);
        }
    }
    const int kg = lane >> 4;
    const float bias = b3[co];
#pragma unroll
    for (int mp = 0; mp < 2; ++mp) {
        const int py = gy * 2 + mp;
#pragma unroll
        for (int p = 0; p < 2; ++p) {
            float v = fmaxf(fmaxf(acc[2 * mp][2 * p], acc[2 * mp][2 * p + 1]),
                            fmaxf(acc[2 * mp + 1][2 * p], acc[2 * mp + 1][2 * p + 1]));
            const int px = kg * 2 + p;
            y3[((size_t)(b * 8 + py) * 8 + px) * 256 + co] = f2b(fmaxf(v + bias, 0.f));
        }
    }
}

// ---------------- conv4 + relu + mean: y3 bf16 NHWC -> feats (16,512) fp32
// block: (cog of 16 co, b); thread = (co_l = tid>>4, px = tid&15)
__global__ __launch_bounds__(256) void k_conv4n(const ushort_t* __restrict__ y3,
                                                const float* __restrict__ wpk4,
                                                const float* __restrict__ b4,
                                                float* __restrict__ feats) {
    const int cog = blockIdx.x, b = blockIdx.y;
    const int tid = threadIdx.x;
    const int px = tid & 15, co_l = tid >> 4;
    const int co = cog * 16 + co_l;
    const int oy = px >> 2, ox = px & 3;

    __shared__ __align__(16) ushort_t s[16384];
    const ushort_t* xb = y3 + (size_t)b * 16384;
    for (int i = tid; i < 8192; i += 256) ((unsigned int*)s)[i] = ((const unsigned int*)xb)[i];
    __syncthreads();

    float acc = 0.f;
    for (int ci8 = 0; ci8 < 32; ++ci8) {
#pragma unroll
        for (int ky = 0; ky < 3; ++ky) {
            const int iy = 2 * oy - 1 + ky;
            if (iy < 0) continue;
#pragma unroll
            for (int kx = 0; kx < 3; ++kx) {
                const int ix = 2 * ox - 1 + kx;
                if (ix < 0) continue;
                const bf16x8 d = *reinterpret_cast<const bf16x8*>(s + (iy * 8 + ix) * 256 + ci8 * 8);
                const float* wp = wpk4 + ((co * 9 + (ky * 3 + kx)) << 8) + ci8 * 8;
                const float4 wa = *(const float4*)wp;
                const float4 wb = *(const float4*)(wp + 4);
                acc += b2f(d[0]) * wa.x + b2f(d[1]) * wa.y + b2f(d[2]) * wa.z + b2f(d[3]) * wa.w
                     + b2f(d[4]) * wb.x + b2f(d[5]) * wb.y + b2f(d[6]) * wb.z + b2f(d[7]) * wb.w;
            }
        }
    }
    float r = fmaxf(acc + b4[co], 0.f);
#pragma unroll
    for (int off = 1; off < 16; off <<= 1) r += __shfl_xor(r, off, 64);
    if ((tid & 15) == 0) feats[b * 512 + co] = r * 0.0625f;
}

// ---------------- head: feats -> logits -> softmax -> VLAD residual v (16, 32768)
__global__ __launch_bounds__(256) void k_head(const float* __restrict__ feats,
                                              const float* __restrict__ wv,
                                              const float* __restrict__ bv,
                                              const float* __restrict__ centroids,
                                              float* __restrict__ v) {
    const int b = blockIdx.x;
    __shared__ float sf[512];
    __shared__ float sl[64];
    __shared__ float sa[64];
    for (int i = threadIdx.x; i < 512; i += 256) sf[i] = feats[b * 512 + i];
    __syncthreads();
    if (threadIdx.x < 64) {
        const int k = threadIdx.x;
        float s = bv[k];
        for (int c = 0; c < 512; ++c) s += sf[c] * wv[(size_t)k * 512 + c];
        sl[k] = s;
    }
    __syncthreads();
    if (threadIdx.x < 64) {
        const int k = threadIdx.x;
        float m = -1e30f;
        for (int i = 0; i < 64; ++i) m = fmaxf(m, sl[i]);
        float sum = 0.f;
        for (int i = 0; i < 64; ++i) sum += __expf(sl[i] - m);
        sa[k] = __expf(sl[k] - m) / sum;
    }
    __syncthreads();
    for (int i4 = threadIdx.x * 4; i4 < 32768; i4 += 1024) {
        const int k = i4 >> 9;
        const float a_ = sa[k];
        const float4 c4 = *(const float4*)(centroids + i4);
        const float4 f4 = *(const float4*)(&sf[i4 & 511]);
        float4 o;
        o.x = a_ * (f4.x - c4.x);
        o.y = a_ * (f4.y - c4.y);
        o.z = a_ * (f4.z - c4.z);
        o.w = a_ * (f4.w - c4.w);
        *(float4*)(v + (size_t)b * 32768 + i4) = o;
    }
}

// ---------------- fc1
__global__ __launch_bounds__(256) void k_fc1(const float* __restrict__ v,
                                             const float* __restrict__ fw1,
                                             const float* __restrict__ fb1,
                                             float* __restrict__ d1) {
    const int d = blockIdx.x;
    float acc[16];
#pragma unroll
    for (int i = 0; i < 16; ++i) acc[i] = 0.f;
    const float* wrow = fw1 + (size_t)d * 32768;
    for (int j4 = threadIdx.x * 4; j4 < 32768; j4 += 1024) {
        const float4 w = *(const float4*)(wrow + j4);
#pragma unroll
        for (int b = 0; b < 16; ++b) {
            const float4 vv = *(const float4*)(v + (size_t)b * 32768 + j4);
            acc[b] += w.x * vv.x + w.y * vv.y + w.z * vv.z + w.w * vv.w;
        }
    }
#pragma unroll
    for (int b = 0; b < 16; ++b) {
        float s = acc[b];
        for (int off = 32; off >= 1; off >>= 1) s += __shfl_down(s, off, 64);
        acc[b] = s;
    }
    __shared__ float red[4][16];
    const int wid = threadIdx.x >> 6, lane = threadIdx.x & 63;
    if (lane == 0) {
#pragma unroll
        for (int b = 0; b < 16; ++b) red[wid][b] = acc[b];
    }
    __syncthreads();
    if (threadIdx.x < 16) {
        const int b = threadIdx.x;
        float s = red[0][b] + red[1][b] + red[2][b] + red[3][b] + fb1[d];
        d1[b * 256 + d] = fmaxf(s, 0.f);
    }
}

// ---------------- fc2 + L2 norm
__global__ __launch_bounds__(256) void k_fc2(const float* __restrict__ d1,
                                             const float* __restrict__ fw2,
                                             const float* __restrict__ fb2,
                                             float* __restrict__ out) {
    const int b = blockIdx.x;
    const int dd = threadIdx.x;
    __shared__ float sd[256];
    __shared__ float sq[256];
    sd[dd] = d1[b * 256 + dd];
    __syncthreads();
    float s = fb2[dd];
    for (int j = 0; j < 256; ++j) s += sd[j] * fw2[(size_t)dd * 256 + j];
    sq[dd] = s * s;
    __syncthreads();
    for (int off = 128; off >= 1; off >>= 1) {
        if (dd < off) sq[dd] += sq[dd + off];
        __syncthreads();
    }
    const float inv = rsqrtf(sq[0]);
    out[b * 256 + dd] = s * inv;
}

extern "C" void kernel_launch(void* const* d_in, const int* in_sizes, int n_in,
                              void* d_out, int out_size, void* d_ws, size_t ws_size,
                              hipStream_t stream) {
    const float* x    = (const float*)d_in[0];
    const float* w1   = (const float*)d_in[1];
    const float* b1   = (const float*)d_in[2];
    const float* w2   = (const float*)d_in[3];
    const float* b2   = (const float*)d_in[4];
    const float* w3   = (const float*)d_in[5];
    const float* b3   = (const float*)d_in[6];
    const float* w4   = (const float*)d_in[7];
    const float* b4   = (const float*)d_in[8];
    const float* wv   = (const float*)d_in[9];
    const float* bv   = (const float*)d_in[10];
    const float* cen  = (const float*)d_in[11];
    const float* fw1  = (const float*)d_in[12];
    const float* fb1  = (const float*)d_in[13];
    const float* fw2  = (const float*)d_in[14];
    const float* fb2  = (const float*)d_in[15];
    float* out = (float*)d_out;

    char* p = (char*)d_ws;
    ushort_t* y1   = (ushort_t*)p; p += 33554432;   // 16*128*128*64 bf16
    ushort_t* y2   = (ushort_t*)p; p += 4194304;    // 16*32*32*128 bf16
    ushort_t* y3   = (ushort_t*)p; p += 524288;     // 16*8*8*256 bf16
    float*    feats= (float*)p;    p += 32768;      // 16*512
    float*    vbuf = (float*)p;    p += 2097152;    // 16*32768
    float*    d1   = (float*)p;    p += 16384;      // 16*256
    ushort_t* wpk2 = (ushort_t*)p; p += 147456;     // 73728 bf16
    ushort_t* wpk3 = (ushort_t*)p; p += 589824;     // 294912 bf16
    float*    wpk4 = (float*)p;    p += 4718592;    // 1179648 f32

    k_pack2<<<36, 256, 0, stream>>>(w2, wpk2);
    k_pack3<<<144, 256, 0, stream>>>(w3, wpk3);
    k_pack4<<<4608, 256, 0, stream>>>(w4, wpk4);
    k_conv1<<<dim3(64, 16), 256, 0, stream>>>(x, w1, b1, y1);
    k_conv2m<<<dim3(32, 16), 256, 0, stream>>>(y1, wpk2, b2, y2);
    k_conv3m<<<dim3(4, 4, 16), 256, 0, stream>>>(y2, wpk3, b3, y3);
    k_conv4n<<<dim3(32, 16), 256, 0, stream>>>(y3, wpk4, b4, feats);
    k_head<<<16, 256, 0, stream>>>(feats, wv, bv, cen, vbuf);
    k_fc1<<<256, 256, 0, stream>>>(vbuf, fw1, fb1, d1);
    k_fc2<<<16, 256, 0, stream>>>(d1, fw2, fb2, out);
}